// Round 6
// baseline (200.944 us; speedup 1.0000x reference)
//
#include <hip/hip_runtime.h>

typedef __bf16 bf16x8 __attribute__((ext_vector_type(8)));
typedef float floatx4 __attribute__((ext_vector_type(4)));

#define XS 136    // LDS row stride in bf16 elements (272 B -> 2-way bank aliasing = free)
#define ROWS 32   // rows per block

__device__ __forceinline__ unsigned short f32_bf16(float f) {
    union { float f; unsigned int u; } c; c.f = f;
    return (unsigned short)((c.u + 0x7fffu + ((c.u >> 16) & 1u)) >> 16);  // RNE, finite inputs
}

// w1 -> MFMA B-fragment order, hidden-col mapping h(nt,l15) = l15*32 + nt.
// frag f = (e*32+nt)*4+ks ; lane (quad,l15) holds B[k=quad*8+j][n=l15] = w1[e][h][k]
__global__ __launch_bounds__(256) void prep_w1_frag(const float* __restrict__ w1,
                                                    unsigned short* __restrict__ wbf) {
    int g    = blockIdx.x * 256 + threadIdx.x;   // 64 blocks -> 16384 threads
    int lane = g & 63;
    int frag = g >> 6;                            // 0..255
    int ks   = frag & 3;
    int nt   = (frag >> 2) & 31;
    int e    = frag >> 7;
    int l15  = lane & 15;
    int quad = lane >> 4;
    int h    = l15 * 32 + nt;
    const float* src = w1 + ((e * 512 + h) * 128 + ks * 32 + quad * 8);
    unsigned short* dst = wbf + (long)g * 8;      // 16 B/lane, contiguous per wave
    #pragma unroll
    for (int j = 0; j < 8; ++j) dst[j] = f32_bf16(src[j]);
}

// Occupancy model (rounds 0/2/5 measured): waves/SIMD halves at VGPR>128;
// (256,N) caps VGPR at 256/N. r5 (VGPR=192, 2 waves/SIMD, Occ 11%) LOST to
// r0 (VGPR=128, 4 waves/SIMD, Occ 21.6%) despite register-resident afrag.
// This round targets the untested winning quadrant: afrag register-resident
// AND VGPR<=128, by shrinking the live set: ROWS=32 -> 2 m-tiles/wave:
// afrag[2][4]=32 + outp[2][4][2]=16 + weight frags 16 + addressing ~90 VGPR.
// (256,2) pins the 128 cap (safe now: live set genuinely fits; r2's spill
// at this cap was a ~150 live set). 4 waves/SIMD = 16 waves/CU; weight L2
// traffic 4096 blocks x 256 KiB = 1 GiB (wbf L2-resident), ~30 us at L2 BW,
// hidden under MFMA+VALU across 16 waves/CU.
__global__ __launch_bounds__(256, 2) void moe_fused(
    const float* __restrict__ x,
    const unsigned short* __restrict__ wbf,   // fragment-ordered bf16 w1
    const float* __restrict__ b1,             // [2][512]
    const float* __restrict__ w2,             // [2][2][512]
    const float* __restrict__ b2,             // [2][2]
    const float* __restrict__ protos,         // [2][128]
    float* __restrict__ out)                  // [B][2]
{
    __shared__ unsigned short xs[ROWS * XS];  // 8704 B
    __shared__ float out_s[2][ROWS][2][2];    // [slice][row][e][o]  1024 B
    __shared__ int   t_s[ROWS];               // 128 B  -> ~9.9 KB total

    const int tid   = threadIdx.x;
    const int lane  = tid & 63;
    const int wave  = tid >> 6;
    const int quad  = lane >> 4;
    const int l15   = lane & 15;
    const int slice = wave & 1;               // nt-half 0/1
    const int e     = wave >> 1;              // expert
    const long rowbase = (long)blockIdx.x * ROWS;

    // ---- routing: t = (d1 < d0) via sign of sum_c (p0-p1)*(0.5*(p0+p1)-x), fp64 ----
    if (tid < 2 * ROWS) {
        int r   = tid >> 1;
        int sub = tid & 1;
        const float* xr = x + (rowbase + r) * 128 + sub * 64;
        const float* p0 = protos + sub * 64;
        const float* p1 = protos + 128 + sub * 64;
        double acc = 0.0;
        #pragma unroll
        for (int k = 0; k < 16; ++k) {
            float4 xv = *(const float4*)(xr + k * 4);
            float4 a  = *(const float4*)(p0 + k * 4);
            float4 b  = *(const float4*)(p1 + k * 4);
            acc += ((double)a.x - b.x) * (0.5 * ((double)a.x + b.x) - xv.x);
            acc += ((double)a.y - b.y) * (0.5 * ((double)a.y + b.y) - xv.y);
            acc += ((double)a.z - b.z) * (0.5 * ((double)a.z + b.z) - xv.z);
            acc += ((double)a.w - b.w) * (0.5 * ((double)a.w + b.w) - xv.w);
        }
        acc += __shfl_xor(acc, 1);
        if (sub == 0) t_s[r] = (acc > 0.0) ? 1 : 0;   // tie -> expert 0 (numpy argmin)
    }

    // ---- stage x tile: coalesced float4 global reads -> bf16 LDS ----
    for (int i = tid; i < ROWS * 32; i += 256) {
        int r  = i >> 5;
        int c4 = (i & 31) * 4;
        float4 v = *(const float4*)(x + (rowbase + r) * 128 + c4);
        ushort4 p;
        p.x = f32_bf16(v.x); p.y = f32_bf16(v.y);
        p.z = f32_bf16(v.z); p.w = f32_bf16(v.w);
        *(ushort4*)&xs[r * XS + c4] = p;
    }
    __syncthreads();

    // ---- A fragments: 2 m-tiles x 4 k-steps, register-resident (one-time LDS read) ----
    // A-operand layout: A[m = lane&15][k = quad*8 + j]
    bf16x8 afrag[2][4];
    #pragma unroll
    for (int mt = 0; mt < 2; ++mt) {
        int r = mt * 16 + l15;
        #pragma unroll
        for (int ks = 0; ks < 4; ++ks)
            afrag[mt][ks] = *(const bf16x8*)&xs[r * XS + ks * 32 + quad * 8];
    }

    float outp[2][4][2] = {};   // [m-tile][reg(row)][o] layer-2 partials

    // ---- main loop: 16 n-tiles (this wave's expert + nt-half), all frags read once ----
    const bf16x8* wb8 = (const bf16x8*)wbf + (long)((e * 32 + slice * 16) * 4) * 64 + lane;
    const int    coff = e * 512 + l15 * 32 + slice * 16;
    const float* b1p  = b1 + coff;
    const float* w2ap = w2 + e * 1024 + l15 * 32 + slice * 16;
    const float* w2bp = w2ap + 512;
    for (int nt = 0; nt < 16; ++nt) {
        const bf16x8* wp = wb8 + nt * 256;
        bf16x8 bf0 = wp[0];
        bf16x8 bf1 = wp[64];
        bf16x8 bf2 = wp[128];
        bf16x8 bf3 = wp[192];
        float bb  = b1p[nt];
        float w2a = w2ap[nt];
        float w2b = w2bp[nt];
        #pragma unroll
        for (int mt = 0; mt < 2; ++mt) {
            floatx4 c = {bb, bb, bb, bb};   // bias folded into accumulator init
            c = __builtin_amdgcn_mfma_f32_16x16x32_bf16(afrag[mt][0], bf0, c, 0, 0, 0);
            c = __builtin_amdgcn_mfma_f32_16x16x32_bf16(afrag[mt][1], bf1, c, 0, 0, 0);
            c = __builtin_amdgcn_mfma_f32_16x16x32_bf16(afrag[mt][2], bf2, c, 0, 0, 0);
            c = __builtin_amdgcn_mfma_f32_16x16x32_bf16(afrag[mt][3], bf3, c, 0, 0, 0);
            #pragma unroll
            for (int rg = 0; rg < 4; ++rg) {
                float h = fmaxf(c[rg], 0.0f);
                outp[mt][rg][0] = fmaf(h, w2a, outp[mt][rg][0]);
                outp[mt][rg][1] = fmaf(h, w2b, outp[mt][rg][1]);
            }
        }
    }

    // ---- reduce layer-2 partials across the 16 column-lanes, write slice buffer ----
    #pragma unroll
    for (int mt = 0; mt < 2; ++mt)
        #pragma unroll
        for (int rg = 0; rg < 4; ++rg) {
            float v0 = outp[mt][rg][0];
            float v1 = outp[mt][rg][1];
            v0 += __shfl_xor(v0, 1);  v1 += __shfl_xor(v1, 1);
            v0 += __shfl_xor(v0, 2);  v1 += __shfl_xor(v1, 2);
            v0 += __shfl_xor(v0, 4);  v1 += __shfl_xor(v1, 4);
            v0 += __shfl_xor(v0, 8);  v1 += __shfl_xor(v1, 8);
            if (l15 == 0) {
                int r = mt * 16 + quad * 4 + rg;   // C/D: row = quad*4 + reg
                out_s[slice][r][e][0] = v0;
                out_s[slice][r][e][1] = v1;
            }
        }
    __syncthreads();

    // ---- select expert per row, combine nt-halves, add b2, coalesced store ----
    if (tid < 2 * ROWS) {
        int r  = tid >> 1;
        int o  = tid & 1;
        int te = t_s[r];
        out[(rowbase + r) * 2 + o] =
            out_s[0][r][te][o] + out_s[1][r][te][o] + b2[te * 2 + o];
    }
}

extern "C" void kernel_launch(void* const* d_in, const int* in_sizes, int n_in,
                              void* d_out, int out_size, void* d_ws, size_t ws_size,
                              hipStream_t stream) {
    const float* x      = (const float*)d_in[0];
    const float* w1     = (const float*)d_in[1];
    const float* b1     = (const float*)d_in[2];
    const float* w2     = (const float*)d_in[3];
    const float* b2     = (const float*)d_in[4];
    const float* protos = (const float*)d_in[5];
    float* out = (float*)d_out;
    unsigned short* wbf = (unsigned short*)d_ws;   // 256 KiB bf16 fragment-ordered w1

    prep_w1_frag<<<dim3(64), dim3(256), 0, stream>>>(w1, wbf);
    moe_fused<<<dim3(4096), dim3(256), 0, stream>>>(x, wbf, b1, w2, b2, protos, out);
}

// Round 7
// 169.781 us; speedup vs baseline: 1.1835x; 1.1835x over previous
//
#include <hip/hip_runtime.h>

typedef __bf16 bf16x8 __attribute__((ext_vector_type(8)));
typedef float floatx4 __attribute__((ext_vector_type(4)));

#define XS 136    // LDS row stride in bf16 elements (272 B -> 2-way bank aliasing = free)
#define ROWS 128  // rows per block

__device__ __forceinline__ unsigned short f32_bf16(float f) {
    union { float f; unsigned int u; } c; c.f = f;
    return (unsigned short)((c.u + 0x7fffu + ((c.u >> 16) & 1u)) >> 16);  // RNE, finite inputs
}

// zero-VGPR async prefetch: global -> LDS, 16 B per lane.
// LDS dest = wave-uniform base + lane*16 (HW); global src is per-lane.
__device__ __forceinline__ void gload_lds16(const unsigned short* g, unsigned short* l) {
    __builtin_amdgcn_global_load_lds(
        (const __attribute__((address_space(1))) void*)g,
        (__attribute__((address_space(3))) void*)l, 16, 0, 0);
}

// w1 -> MFMA B-fragment order, hidden-col mapping h(g,l15) = l15*32 + (g&31), e = g>>5.
// frag f = g*4+ks ; lane (quad,l15) holds B[k=quad*8+j][n=l15]
__global__ __launch_bounds__(256) void prep_w1_frag(const float* __restrict__ w1,
                                                    unsigned short* __restrict__ wbf) {
    int g    = blockIdx.x * 256 + threadIdx.x;   // 64 blocks -> 16384 threads
    int lane = g & 63;
    int frag = g >> 6;                            // 0..255
    int ks   = frag & 3;
    int nt   = (frag >> 2) & 31;
    int e    = frag >> 7;
    int l15  = lane & 15;
    int quad = lane >> 4;
    int h    = l15 * 32 + nt;
    const float* src = w1 + ((e * 512 + h) * 128 + ks * 32 + quad * 8);
    unsigned short* dst = wbf + (long)g * 8;      // 16 B/lane, contiguous per wave
    #pragma unroll
    for (int j = 0; j < 8; ++j) dst[j] = f32_bf16(src[j]);
}

// Round-7 structure (lesson r0/r5/r6: perf tracks per-wave amortization of the
// per-step weight-load latency, NOT afrag residency or occupancy alone).
// All 4 waves work the SAME hidden-col group per step: wave w owns rows
// w*32..w*32+31 (afrag[2][4]=32 VGPR, loaded ONCE, truly resident), and the
// step's 4 shared weight fragments are staged into an LDS double-buffer with
// global_load_lds (zero VGPR cost), issued one step (2 groups) ahead and
// drained by the step barrier. Weight traffic: 1024 blocks x 256 KiB = 256 MiB
// (= r0). afrag LDS re-reads (512 b128/wave in r0) are gone. LDS: wbuf(16 KB)
// aliases dead xs region -> 37.4 KB total -> 4 blocks/CU; live VGPR ~110
// under the (256,2) 128 cap -> 16 waves/CU static.
__global__ __launch_bounds__(256, 2) void moe_fused(
    const float* __restrict__ x,
    const unsigned short* __restrict__ wbf,   // fragment-ordered bf16 w1
    const float* __restrict__ b1,             // [2][512]
    const float* __restrict__ w2,             // [2][2][512]
    const float* __restrict__ b2,             // [2][2]
    const float* __restrict__ protos,         // [2][128]
    float* __restrict__ out)                  // [B][2]
{
    __shared__ __align__(16) unsigned char smem0[ROWS * XS * 2];  // 34816 B
    __shared__ float out_s[ROWS][2][2];       // [row][e][o] 2048 B
    __shared__ int   t_s[ROWS];               // 512 B  -> 37376 B total

    unsigned short* xs   = (unsigned short*)smem0;   // x tile (prologue only)
    unsigned short* wbuf = (unsigned short*)smem0;   // [2 buf][2 sub][4 frag][64 lane][8]
                                                     // = 16384 B, aliases dead xs

    const int tid   = threadIdx.x;
    const int lane  = tid & 63;
    const int wave  = tid >> 6;
    const int quad  = lane >> 4;
    const int l15   = lane & 15;
    const long rowbase = (long)blockIdx.x * ROWS;

    // ---- routing: t = (d1 < d0) via sign of sum_c (p0-p1)*(0.5*(p0+p1)-x), fp64 ----
    {
        int r   = tid >> 1;                   // 2 threads per row
        int sub = tid & 1;
        const float* xr = x + (rowbase + r) * 128 + sub * 64;
        const float* p0 = protos + sub * 64;
        const float* p1 = protos + 128 + sub * 64;
        double acc = 0.0;
        #pragma unroll
        for (int k = 0; k < 16; ++k) {
            float4 xv = *(const float4*)(xr + k * 4);
            float4 a  = *(const float4*)(p0 + k * 4);
            float4 b  = *(const float4*)(p1 + k * 4);
            acc += ((double)a.x - b.x) * (0.5 * ((double)a.x + b.x) - xv.x);
            acc += ((double)a.y - b.y) * (0.5 * ((double)a.y + b.y) - xv.y);
            acc += ((double)a.z - b.z) * (0.5 * ((double)a.z + b.z) - xv.z);
            acc += ((double)a.w - b.w) * (0.5 * ((double)a.w + b.w) - xv.w);
        }
        acc += __shfl_xor(acc, 1);
        if (sub == 0) t_s[r] = (acc > 0.0) ? 1 : 0;   // tie -> expert 0 (numpy argmin)
    }

    // ---- stage x tile: coalesced float4 global reads -> bf16 LDS ----
    for (int i = tid; i < ROWS * 32; i += 256) {
        int r  = i >> 5;
        int c4 = (i & 31) * 4;
        float4 v = *(const float4*)(x + (rowbase + r) * 128 + c4);
        ushort4 p;
        p.x = f32_bf16(v.x); p.y = f32_bf16(v.y);
        p.z = f32_bf16(v.z); p.w = f32_bf16(v.w);
        *(ushort4*)&xs[r * XS + c4] = p;
    }
    __syncthreads();

    // ---- A fragments: wave-private 32 rows = 2 m-tiles x 4 k-steps, read ONCE ----
    // A-operand layout: A[m = lane&15][k = quad*8 + j]
    bf16x8 afrag[2][4];
    #pragma unroll
    for (int mt = 0; mt < 2; ++mt) {
        int r = wave * 32 + mt * 16 + l15;
        #pragma unroll
        for (int ks = 0; ks < 4; ++ks)
            afrag[mt][ks] = *(const bf16x8*)&xs[r * XS + ks * 32 + quad * 8];
    }
    __syncthreads();   // xs dead from here; wbuf may overwrite it

    // ---- prologue: stage groups 0,1 into buf0 (each wave stages fragment 'wave') ----
    gload_lds16(wbf + ((size_t)((0 * 4 + wave) * 64 + lane)) * 8,
                wbuf + 0 * 4096 + 0 * 2048 + wave * 512);
    gload_lds16(wbf + ((size_t)((1 * 4 + wave) * 64 + lane)) * 8,
                wbuf + 0 * 4096 + 1 * 2048 + wave * 512);
    __syncthreads();   // vmcnt drained before barrier -> buf0 ready

    float outp[2][2][4][2] = {};   // [e][m-tile][reg(row)][o] layer-2 partials

    // ---- main loop: 32 steps x 2 col-groups; stage step+1 while computing step ----
    #pragma unroll
    for (int e = 0; e < 2; ++e) {
        const float* b1p  = b1 + e * 512 + l15 * 32;
        const float* w2ap = w2 + e * 1024 + l15 * 32;
        const float* w2bp = w2ap + 512;
        for (int p = 0; p < 16; ++p) {
            const int pp  = e * 16 + p;       // global step 0..31
            const int buf = pp & 1;
            const unsigned short* wb = wbuf + buf * 4096;
            if (pp < 31) {                    // prefetch next step's 2 groups
                const int gn = pp * 2 + 2;
                unsigned short* db = wbuf + (buf ^ 1) * 4096 + wave * 512;
                gload_lds16(wbf + ((size_t)(((gn    ) * 4 + wave) * 64 + lane)) * 8, db);
                gload_lds16(wbf + ((size_t)(((gn + 1) * 4 + wave) * 64 + lane)) * 8, db + 2048);
            }
            #pragma unroll
            for (int s = 0; s < 2; ++s) {
                const int ntl = p * 2 + s;
                float bb  = b1p[ntl];
                float w2a = w2ap[ntl];
                float w2b = w2bp[ntl];
                floatx4 c0 = {bb, bb, bb, bb};
                floatx4 c1 = {bb, bb, bb, bb};
                #pragma unroll
                for (int ks = 0; ks < 4; ++ks) {
                    bf16x8 bw = *(const bf16x8*)(wb + s * 2048 + ks * 512 + lane * 8);
                    c0 = __builtin_amdgcn_mfma_f32_16x16x32_bf16(afrag[0][ks], bw, c0, 0, 0, 0);
                    c1 = __builtin_amdgcn_mfma_f32_16x16x32_bf16(afrag[1][ks], bw, c1, 0, 0, 0);
                }
                #pragma unroll
                for (int rg = 0; rg < 4; ++rg) {
                    float h0 = fmaxf(c0[rg], 0.0f);
                    float h1 = fmaxf(c1[rg], 0.0f);
                    outp[e][0][rg][0] = fmaf(h0, w2a, outp[e][0][rg][0]);
                    outp[e][0][rg][1] = fmaf(h0, w2b, outp[e][0][rg][1]);
                    outp[e][1][rg][0] = fmaf(h1, w2a, outp[e][1][rg][0]);
                    outp[e][1][rg][1] = fmaf(h1, w2b, outp[e][1][rg][1]);
                }
            }
            __syncthreads();   // drains prefetch (issued before compute) + buffer swap
        }
    }

    // ---- reduce layer-2 partials across the 16 column-lanes, write out_s ----
    #pragma unroll
    for (int e = 0; e < 2; ++e)
        #pragma unroll
        for (int mt = 0; mt < 2; ++mt)
            #pragma unroll
            for (int rg = 0; rg < 4; ++rg) {
                float v0 = outp[e][mt][rg][0];
                float v1 = outp[e][mt][rg][1];
                v0 += __shfl_xor(v0, 1);  v1 += __shfl_xor(v1, 1);
                v0 += __shfl_xor(v0, 2);  v1 += __shfl_xor(v1, 2);
                v0 += __shfl_xor(v0, 4);  v1 += __shfl_xor(v1, 4);
                v0 += __shfl_xor(v0, 8);  v1 += __shfl_xor(v1, 8);
                if (l15 == 0) {
                    int r = wave * 32 + mt * 16 + quad * 4 + rg;  // C/D: row = quad*4 + reg
                    out_s[r][e][0] = v0;
                    out_s[r][e][1] = v1;
                }
            }
    __syncthreads();

    // ---- select expert per row, add b2, coalesced store ----
    {
        int r  = tid >> 1;
        int o  = tid & 1;
        int te = t_s[r];
        out[(rowbase + r) * 2 + o] = out_s[r][te][o] + b2[te * 2 + o];
    }
}

extern "C" void kernel_launch(void* const* d_in, const int* in_sizes, int n_in,
                              void* d_out, int out_size, void* d_ws, size_t ws_size,
                              hipStream_t stream) {
    const float* x      = (const float*)d_in[0];
    const float* w1     = (const float*)d_in[1];
    const float* b1     = (const float*)d_in[2];
    const float* w2     = (const float*)d_in[3];
    const float* b2     = (const float*)d_in[4];
    const float* protos = (const float*)d_in[5];
    float* out = (float*)d_out;
    unsigned short* wbf = (unsigned short*)d_ws;   // 256 KiB bf16 fragment-ordered w1

    prep_w1_frag<<<dim3(64), dim3(256), 0, stream>>>(w1, wbf);
    moe_fused<<<dim3(1024), dim3(256), 0, stream>>>(x, wbf, b1, w2, b2, protos, out);
}